// Round 1
// 300.550 us; speedup vs baseline: 1.1125x; 1.1125x over previous
//
#include <hip/hip_runtime.h>

#define HNEG (-1000000000.0f)

constexpr int Nc = 128;
constexpr int Mc = 128;
constexpr int CELLS = Nc * Mc * 3;

__device__ __forceinline__ float lse3(float a, float b, float c) {
  float mx = fmaxf(fmaxf(a, b), c);
  return mx + __logf(__expf(a - mx) + __expf(b - mx) + __expf(c - mx));
}

// Compact diagonal-major layout: diag d (= i+j) holds cells j = lo(d)..hi(d),
// stored at (offd(d) + j - lod(d)) * 3 + s within a batch block of CELLS floats.
__device__ __forceinline__ int lod(int d) { return d > 127 ? d - 127 : 0; }
__device__ __forceinline__ int offd(int d) {
  return d <= 128 ? ((d * (d + 1)) >> 1)
                  : 8256 + (d - 128) * 127 - (((d - 128) * (d - 129)) >> 1);
}

// ---------------------------------------------------------------------------
// K1: theta row-major -> theta_diag (compact diag-major). 64x64 LDS tiles.
// ---------------------------------------------------------------------------
__global__ __launch_bounds__(256) void transpose_kernel(
    const float* __restrict__ theta, float* __restrict__ thd) {
  const int b = blockIdx.x;
  const int tile = blockIdx.y;  // 0..3
  const int i0 = (tile >> 1) * 64, j0 = (tile & 1) * 64;
  const int t = threadIdx.x;
  __shared__ float lds[64 * 192];
  const float* src = theta + (size_t)b * CELLS;
  float* dst = thd + (size_t)b * CELLS;
  for (int f = t; f < 64 * 192; f += 256) {
    const int r = f / 192, c = f % 192;
    lds[f] = src[((i0 + r) * Mc + j0) * 3 + c];
  }
  __syncthreads();
  const int g = t >> 6, w = t & 63;
  for (int ld = g; ld < 127; ld += 4) {
    const int d = i0 + j0 + ld;
    const int ljlo = ld > 63 ? ld - 63 : 0;
    const int ljhi = ld < 63 ? ld : 63;
    const int L = (ljhi - ljlo + 1) * 3;
    const int base = (offd(d) + (j0 + ljlo) - lod(d)) * 3;
    for (int e = w; e < L; e += 64) {
      const int lj = ljlo + e / 3, s = e - (e / 3) * 3;
      dst[base + e] = lds[(ld - lj) * 192 + lj * 3 + s];
    }
  }
}

// 6 named scalars per pipeline slot (2 cols x 3 states)
#define DECL6(p) float p##0, p##1, p##2, p##3, p##4, p##5

// ---------------------------------------------------------------------------
// K2: fused fwd || bwd wavefront. One block of 128 threads per batch:
// wave 0 runs the forward recurrence (alpha -> ad diag-major, logZ),
// wave 1 runs the backward recurrence (g = beta written ROW-major into out).
// beta does not depend on alpha, so the two serial chains overlap in time.
// ---------------------------------------------------------------------------

#define F2LOAD(P, dd) do {                                                     \
    const int dc_ = (dd) > 254 ? 254 : (dd);                                   \
    const float* p_ = thd + (size_t)(offd(dc_) + jA - lod(dc_)) * 3;           \
    P##0 = p_[0]; P##1 = p_[1]; P##2 = p_[2];                                  \
    P##3 = p_[3]; P##4 = p_[4]; P##5 = p_[5];                                  \
  } while (0)

#define F2STEP(P, dd) do {                                                     \
    const int iA_ = (dd) - jA, iB_ = (dd) - jB;                                \
    const int base_ = (offd(dd) + jA - lod(dd)) * 3;                           \
    float g0 = mS2 + __logf(wS20 * E00 + wS21 * E10 + wS22 * E20);             \
    float g1 = mPA + __logf(wPA0 * E01 + wPA1 * E11 + wPA2 * E21);             \
    float g2 = mS1 + __logf(wS10 * E02 + wS11 * E12 + wS12 * E22);             \
    if ((dd) == 0 && l == 0) g0 = 0.0f; /* origin: lse_m := 0 at (0,0) */      \
    float cA0 = HNEG, cA1 = HNEG, cA2 = HNEG;                                  \
    if ((unsigned)iA_ < (unsigned)Nc) {                                        \
      cA0 = P##0 + g0; cA1 = P##1 + g1; cA2 = P##2 + g2;                       \
      ad[base_ + 0] = cA0; ad[base_ + 1] = cA1; ad[base_ + 2] = cA2;           \
    }                                                                          \
    float h0 = mPP + __logf(wPP0 * E00 + wPP1 * E10 + wPP2 * E20);             \
    float h1 = mPB + __logf(wPB0 * E01 + wPB1 * E11 + wPB2 * E21);             \
    float h2 = mPA + __logf(wPA0 * E02 + wPA1 * E12 + wPA2 * E22);             \
    float cB0 = HNEG, cB1 = HNEG, cB2 = HNEG;                                  \
    if ((unsigned)iB_ < (unsigned)Nc) {                                        \
      cB0 = P##3 + h0; cB1 = P##4 + h1; cB2 = P##5 + h2;                       \
      ad[base_ + 3] = cB0; ad[base_ + 4] = cB1; ad[base_ + 5] = cB2;           \
    }                                                                          \
    if ((dd) == 254) { fz0 = cB0; fz1 = cB1; fz2 = cB2; }                      \
    const float mA_ = fmaxf(fmaxf(cA0, cA1), cA2);                             \
    const float a0_ = __expf(cA0 - mA_), a1_ = __expf(cA1 - mA_),              \
                a2_ = __expf(cA2 - mA_);                                       \
    const float mB_ = fmaxf(fmaxf(cB0, cB1), cB2);                             \
    const float b0_ = __expf(cB0 - mB_), b1_ = __expf(cB1 - mB_),              \
                b2_ = __expf(cB2 - mB_);                                       \
    mPP = mPA; wPP0 = wPA0; wPP1 = wPA1; wPP2 = wPA2;                          \
    mPA = mA_; wPA0 = a0_; wPA1 = a1_; wPA2 = a2_;                             \
    mPB = mB_; wPB0 = b0_; wPB1 = b1_; wPB2 = b2_;                             \
    mS2 = mS1; wS20 = wS10; wS21 = wS11; wS22 = wS12;                          \
    mS1 = __shfl_up(mB_, 1);                                                   \
    wS10 = __shfl_up(b0_, 1); wS11 = __shfl_up(b1_, 1);                        \
    wS12 = __shfl_up(b2_, 1);                                                  \
    if (l == 0) { mS1 = HNEG; wS10 = 1.f; wS11 = 1.f; wS12 = 1.f; }            \
  } while (0)

// backward-lite: no alpha loads, no logZ; stores g (=beta) row-major into ob.
#define B2LOADL(Pt, dd) do {                                                   \
    int dor_ = 254 - (dd); if (dor_ < 0) dor_ = 0;                             \
    const int base_ = (offd(dor_) + jjB - lod(dor_)) * 3;                      \
    const float* p_ = thd + base_;                                             \
    Pt##3 = p_[0]; Pt##4 = p_[1]; Pt##5 = p_[2];                               \
    Pt##0 = p_[3]; Pt##1 = p_[4]; Pt##2 = p_[5];                               \
  } while (0)

#define B2STEPL(Pt, dd) do {                                                   \
    const int iA_ = Nc - 1 - (dd) + jA;                                        \
    const int iB_ = Nc - 1 - (dd) + jB;                                        \
    float uA0 = HNEG, uA1 = HNEG, uA2 = HNEG;                                  \
    {                                                                          \
      const float v0 = S2u0, v1 = pAu1, v2 = S1u2;                             \
      const float mv = fmaxf(fmaxf(v0, v1), v2);                               \
      const float w0 = __expf(v0 - mv), w1 = __expf(v1 - mv),                  \
                  w2 = __expf(v2 - mv);                                        \
      float g0 = mv + __logf(w0 * E00 + w1 * E01 + w2 * E02);                  \
      float g1 = mv + __logf(w0 * E10 + w1 * E11 + w2 * E12);                  \
      float g2 = mv + __logf(w0 * E20 + w1 * E21 + w2 * E22);                  \
      if ((dd) == 0 && l == 0) { g0 = 0.f; g1 = 0.f; g2 = 0.f; }               \
      if ((unsigned)iA_ < (unsigned)Nc) {                                      \
        uA0 = g0 + Pt##0; uA1 = g1 + Pt##1; uA2 = g2 + Pt##2;                  \
        float* o_ = ob + (iA_ * Mc + jjA) * 3;                                 \
        o_[0] = g0; o_[1] = g1; o_[2] = g2;                                    \
      }                                                                        \
    }                                                                          \
    float uB0 = HNEG, uB1 = HNEG, uB2 = HNEG;                                  \
    {                                                                          \
      const float v0 = ppAu0, v1 = pBu1, v2 = pAu2;                            \
      const float mv = fmaxf(fmaxf(v0, v1), v2);                               \
      const float w0 = __expf(v0 - mv), w1 = __expf(v1 - mv),                  \
                  w2 = __expf(v2 - mv);                                        \
      const float g0 = mv + __logf(w0 * E00 + w1 * E01 + w2 * E02);            \
      const float g1 = mv + __logf(w0 * E10 + w1 * E11 + w2 * E12);            \
      const float g2 = mv + __logf(w0 * E20 + w1 * E21 + w2 * E22);            \
      if ((unsigned)iB_ < (unsigned)Nc) {                                      \
        uB0 = g0 + Pt##3; uB1 = g1 + Pt##4; uB2 = g2 + Pt##5;                  \
        float* o_ = ob + (iB_ * Mc + jjB) * 3;                                 \
        o_[0] = g0; o_[1] = g1; o_[2] = g2;                                    \
      }                                                                        \
    }                                                                          \
    ppAu0 = pAu0; pAu0 = uA0; pAu1 = uA1; pAu2 = uA2; pBu1 = uB1;              \
    S2u0 = S1u0;                                                               \
    S1u0 = __shfl_up(uB0, 1);                                                  \
    S1u2 = __shfl_up(uB2, 1);                                                  \
    if (l == 0) { S1u0 = HNEG; S1u2 = HNEG; }                                  \
  } while (0)

__global__ __launch_bounds__(128, 1) void fb2_kernel(
    const float* __restrict__ thd_, const float* __restrict__ A,
    float* __restrict__ ad_, float* __restrict__ logZ_ws,
    float* __restrict__ ob_) {
  const int b = blockIdx.x;
  const int wave = threadIdx.x >> 6;
  const int l = threadIdx.x & 63;
  const float* thd = thd_ + (size_t)b * CELLS;
  const float* Ab = A + b * 9;
  const float E00 = __expf(Ab[0]), E01 = __expf(Ab[1]), E02 = __expf(Ab[2]);
  const float E10 = __expf(Ab[3]), E11 = __expf(Ab[4]), E12 = __expf(Ab[5]);
  const float E20 = __expf(Ab[6]), E21 = __expf(Ab[7]), E22 = __expf(Ab[8]);

  const int jA = 2 * l, jB = 2 * l + 1;

  if (wave == 0) {
    // ----------------- forward -----------------
    float* ad = ad_ + (size_t)b * CELLS;

    float mPA = HNEG, wPA0 = 1.f, wPA1 = 1.f, wPA2 = 1.f;
    float mPB = HNEG, wPB0 = 1.f, wPB1 = 1.f, wPB2 = 1.f;
    float mPP = HNEG, wPP0 = 1.f, wPP1 = 1.f, wPP2 = 1.f;
    float mS1 = HNEG, wS10 = 1.f, wS11 = 1.f, wS12 = 1.f;
    float mS2 = HNEG, wS20 = 1.f, wS21 = 1.f, wS22 = 1.f;
    float fz0 = HNEG, fz1 = HNEG, fz2 = HNEG;

    DECL6(xt0); DECL6(xt1); DECL6(xt2); DECL6(xt3);
    DECL6(yt0); DECL6(yt1); DECL6(yt2); DECL6(yt3);

    F2LOAD(xt0, 0); F2LOAD(xt1, 1); F2LOAD(xt2, 2); F2LOAD(xt3, 3);
    F2LOAD(yt0, 4); F2LOAD(yt1, 5); F2LOAD(yt2, 6); F2LOAD(yt3, 7);

    for (int t = 0; t < 32; ++t) {
      const int d0 = 8 * t;
      F2STEP(xt0, d0 + 0); F2STEP(xt1, d0 + 1); F2STEP(xt2, d0 + 2); F2STEP(xt3, d0 + 3);
      F2LOAD(xt0, d0 + 8); F2LOAD(xt1, d0 + 9); F2LOAD(xt2, d0 + 10); F2LOAD(xt3, d0 + 11);
      F2STEP(yt0, d0 + 4); F2STEP(yt1, d0 + 5); F2STEP(yt2, d0 + 6); F2STEP(yt3, d0 + 7);
      F2LOAD(yt0, d0 + 12); F2LOAD(yt1, d0 + 13); F2LOAD(yt2, d0 + 14); F2LOAD(yt3, d0 + 15);
    }
    if (l == 63) logZ_ws[b] = lse3(fz0, fz1, fz2);
  } else {
    // ----------------- backward (beta only) -----------------
    float* ob = ob_ + (size_t)b * CELLS;
    const int jjA = Mc - 1 - jA, jjB = Mc - 1 - jB;  // orig cols

    float pAu0 = HNEG, pAu1 = HNEG, pAu2 = HNEG;
    float ppAu0 = HNEG, pBu1 = HNEG;
    float S1u0 = HNEG, S1u2 = HNEG, S2u0 = HNEG;

    DECL6(xt0); DECL6(xt1); DECL6(xt2); DECL6(xt3);
    DECL6(yt0); DECL6(yt1); DECL6(yt2); DECL6(yt3);

    B2LOADL(xt0, 0); B2LOADL(xt1, 1); B2LOADL(xt2, 2); B2LOADL(xt3, 3);
    B2LOADL(yt0, 4); B2LOADL(yt1, 5); B2LOADL(yt2, 6); B2LOADL(yt3, 7);

    for (int t = 0; t < 32; ++t) {
      const int d0 = 8 * t;
      B2STEPL(xt0, d0 + 0); B2STEPL(xt1, d0 + 1);
      B2STEPL(xt2, d0 + 2); B2STEPL(xt3, d0 + 3);
      B2LOADL(xt0, d0 + 8); B2LOADL(xt1, d0 + 9);
      B2LOADL(xt2, d0 + 10); B2LOADL(xt3, d0 + 11);
      B2STEPL(yt0, d0 + 4); B2STEPL(yt1, d0 + 5);
      B2STEPL(yt2, d0 + 6); B2STEPL(yt3, d0 + 7);
      B2LOADL(yt0, d0 + 12); B2LOADL(yt1, d0 + 13);
      B2LOADL(yt2, d0 + 14); B2LOADL(yt3, d0 + 15);
    }
  }
}

// ---------------------------------------------------------------------------
// K3: combine. out currently holds g (=beta) row-major; alpha is diag-major
// in ad. Tile-transpose alpha through LDS (inverse of K1), then
// out = g + alpha - logZ with fully coalesced reads and writes.
// ---------------------------------------------------------------------------
__global__ __launch_bounds__(256) void combine_kernel(
    const float* __restrict__ ad_, const float* __restrict__ logZ_ws,
    float* __restrict__ out_) {
  const int b = blockIdx.x;
  const int tile = blockIdx.y;  // 0..3
  const int i0 = (tile >> 1) * 64, j0 = (tile & 1) * 64;
  const int t = threadIdx.x;
  __shared__ float lds[64 * 192];
  const float* src = ad_ + (size_t)b * CELLS;
  float* dst = out_ + (size_t)b * CELLS;
  const float logZ = logZ_ws[b];
  // diag-major (coalesced segments) -> LDS row-major
  const int g = t >> 6, w = t & 63;
  for (int ld = g; ld < 127; ld += 4) {
    const int d = i0 + j0 + ld;
    const int ljlo = ld > 63 ? ld - 63 : 0;
    const int ljhi = ld < 63 ? ld : 63;
    const int L = (ljhi - ljlo + 1) * 3;
    const int base = (offd(d) + (j0 + ljlo) - lod(d)) * 3;
    for (int e = w; e < L; e += 64) {
      const int lj = ljlo + e / 3, s = e - (e / 3) * 3;
      lds[(ld - lj) * 192 + lj * 3 + s] = src[base + e];
    }
  }
  __syncthreads();
  // row-major coalesced: out = g + alpha - logZ
  for (int f = t; f < 64 * 192; f += 256) {
    const int r = f / 192, c = f % 192;
    const size_t o = ((size_t)(i0 + r) * Mc + j0) * 3 + c;
    dst[o] = dst[o] + lds[f] - logZ;
  }
}

// ---------------------------------------------------------------------------
// Fallback (round-2 structure, known-correct ~355 us): used only if ws small.
// ---------------------------------------------------------------------------
__global__ __launch_bounds__(128) void fwd_fb(const float* __restrict__ theta,
                                              const float* __restrict__ A,
                                              float* __restrict__ out) {
  const int b = blockIdx.x;
  const int j = threadIdx.x;
  const float* th = theta + (size_t)b * CELLS;
  float* ob = out + (size_t)b * CELLS;

  __shared__ float sA[9];
  __shared__ float ring[3][Mc + 1][3];
  if (j < 9) sA[j] = A[b * 9 + j];
  {
    float* rf = &ring[0][0][0];
    for (int t = j; t < 3 * (Mc + 1) * 3; t += Mc) rf[t] = HNEG;
  }
  __syncthreads();
  const float A00 = sA[0], A01 = sA[1], A02 = sA[2];
  const float A10 = sA[3], A11 = sA[4], A12 = sA[5];
  const float A20 = sA[6], A21 = sA[7], A22 = sA[8];

  float p0 = HNEG, p1 = HNEG, p2 = HNEG;
  float tc0 = 0.f, tc1 = 0.f, tc2 = 0.f, tn0 = 0.f, tn1 = 0.f, tn2 = 0.f;
  if (j == 0) { tc0 = th[0]; tc1 = th[1]; tc2 = th[2]; }
  if (j <= 1) {
    const int i1 = 1 - j;
    const float* p = th + (i1 * Mc + j) * 3;
    tn0 = p[0]; tn1 = p[1]; tn2 = p[2];
  }
  int s0 = 0, s1 = 2, s2 = 1;
  for (int d = 0; d < Nc + Mc - 1; ++d) {
    const int i = d - j;
    float tf0 = 0.f, tf1 = 0.f, tf2 = 0.f;
    const int ip = i + 2;
    if (ip >= 0 && ip < Nc) {
      const float* p = th + (ip * Mc + j) * 3;
      tf0 = p[0]; tf1 = p[1]; tf2 = p[2];
    }
    float c0 = HNEG, c1 = HNEG, c2 = HNEG;
    if (i >= 0 && i < Nc) {
      const float* nd1 = ring[s1][j];
      const float* nd2 = ring[s2][j];
      float lm = lse3(nd2[0] + A00, nd2[1] + A10, nd2[2] + A20);
      if (i == 0 && j == 0) lm = 0.0f;
      float lx = lse3(p0 + A01, p1 + A11, p2 + A21);
      float ly = lse3(nd1[0] + A02, nd1[1] + A12, nd1[2] + A22);
      c0 = tc0 + lm; c1 = tc1 + lx; c2 = tc2 + ly;
      float* o = ob + (i * Mc + j) * 3;
      o[0] = c0; o[1] = c1; o[2] = c2;
    }
    float* w = ring[s0][j + 1];
    w[0] = c0; w[1] = c1; w[2] = c2;
    __syncthreads();
    p0 = c0; p1 = c1; p2 = c2;
    tc0 = tn0; tc1 = tn1; tc2 = tn2;
    tn0 = tf0; tn1 = tf1; tn2 = tf2;
    const int t = s2; s2 = s1; s1 = s0; s0 = t;
  }
}

__global__ __launch_bounds__(128) void bwd_fb(const float* __restrict__ theta,
                                              const float* __restrict__ A,
                                              float* __restrict__ ob_) {
  const int b = blockIdx.x;
  const int q = threadIdx.x;
  const float* th = theta + (size_t)b * CELLS;
  float* ob = ob_ + (size_t)b * CELLS;

  __shared__ float sA[9];
  __shared__ float ring[3][Mc + 1][3];
  __shared__ float sZ;
  if (q < 9) sA[q] = A[b * 9 + q];
  {
    float* rf = &ring[0][0][0];
    for (int t = q; t < 3 * (Mc + 1) * 3; t += Mc) rf[t] = HNEG;
  }
  if (q == 0) {
    sZ = lse3(ob[(Nc * Mc - 1) * 3 + 0], ob[(Nc * Mc - 1) * 3 + 1],
              ob[(Nc * Mc - 1) * 3 + 2]);
  }
  __syncthreads();
  const float A00 = sA[0], A01 = sA[1], A02 = sA[2];
  const float A10 = sA[3], A11 = sA[4], A12 = sA[5];
  const float A20 = sA[6], A21 = sA[7], A22 = sA[8];
  const float logZ = sZ;

  const int jj = Mc - 1 - q;
  float pu1 = HNEG;
  float tc0 = 0.f, tc1 = 0.f, tc2 = 0.f, tn0 = 0.f, tn1 = 0.f, tn2 = 0.f;
  float ac0 = 0.f, ac1 = 0.f, ac2 = 0.f, an0 = 0.f, an1 = 0.f, an2 = 0.f;
  if (q == 0) {
    const float* p = th + ((Nc - 1) * Mc + jj) * 3;
    tc0 = p[0]; tc1 = p[1]; tc2 = p[2];
    const float* a = ob + ((Nc - 1) * Mc + jj) * 3;
    ac0 = a[0]; ac1 = a[1]; ac2 = a[2];
  }
  if (q <= 1) {
    const int i1 = Nc - 2 + q;
    const float* p = th + (i1 * Mc + jj) * 3;
    tn0 = p[0]; tn1 = p[1]; tn2 = p[2];
    const float* a = ob + (i1 * Mc + jj) * 3;
    an0 = a[0]; an1 = a[1]; an2 = a[2];
  }
  int s0 = 0, s1 = 2, s2 = 1;
  for (int d = 0; d < Nc + Mc - 1; ++d) {
    const int p = d - q;
    const int i = Nc - 1 - p;
    float tf0 = 0.f, tf1 = 0.f, tf2 = 0.f, af0 = 0.f, af1 = 0.f, af2 = 0.f;
    const int ipf = i - 2;
    if (ipf >= 0 && ipf < Nc) {
      const float* pp = th + (ipf * Mc + jj) * 3;
      tf0 = pp[0]; tf1 = pp[1]; tf2 = pp[2];
      const float* aa = ob + (ipf * Mc + jj) * 3;
      af0 = aa[0]; af1 = aa[1]; af2 = aa[2];
    }
    float u0 = HNEG, u1 = HNEG, u2 = HNEG;
    if (p >= 0 && p < Nc) {
      const float* nd1 = ring[s1][q];
      const float* nd2 = ring[s2][q];
      const float v0 = nd2[0];
      const float v1 = pu1;
      const float v2 = nd1[2];
      float g0 = lse3(A00 + v0, A01 + v1, A02 + v2);
      float g1 = lse3(A10 + v0, A11 + v1, A12 + v2);
      float g2 = lse3(A20 + v0, A21 + v1, A22 + v2);
      if (p == 0 && q == 0) { g0 = 0.0f; g1 = 0.0f; g2 = 0.0f; }
      u0 = g0 + tc0; u1 = g1 + tc1; u2 = g2 + tc2;
      float* o = ob + (i * Mc + jj) * 3;
      o[0] = ac0 + g0 - logZ;
      o[1] = ac1 + g1 - logZ;
      o[2] = ac2 + g2 - logZ;
    }
    float* w = ring[s0][q + 1];
    w[0] = u0; w[1] = u1; w[2] = u2;
    __syncthreads();
    pu1 = u1;
    tc0 = tn0; tc1 = tn1; tc2 = tn2;
    tn0 = tf0; tn1 = tf1; tn2 = tf2;
    ac0 = an0; ac1 = an1; ac2 = an2;
    an0 = af0; an1 = af1; an2 = af2;
    const int t = s2; s2 = s1; s1 = s0; s0 = t;
  }
}

extern "C" void kernel_launch(void* const* d_in, const int* in_sizes, int n_in,
                              void* d_out, int out_size, void* d_ws, size_t ws_size,
                              hipStream_t stream) {
  const float* theta = (const float*)d_in[0];
  const float* A = (const float*)d_in[1];
  float* out = (float*)d_out;
  const int B = in_sizes[1] / 9;  // A is (B, 3, 3)

  const size_t need = (size_t)B * CELLS * 8 + (size_t)B * 4;  // thd + ad + logZ
  if (ws_size >= need) {
    float* thd = (float*)d_ws;
    float* ad = thd + (size_t)B * CELLS;
    float* logZ_ws = ad + (size_t)B * CELLS;
    transpose_kernel<<<dim3(B, 4), dim3(256), 0, stream>>>(theta, thd);
    fb2_kernel<<<dim3(B), dim3(128), 0, stream>>>(thd, A, ad, logZ_ws, out);
    combine_kernel<<<dim3(B, 4), dim3(256), 0, stream>>>(ad, logZ_ws, out);
  } else {
    fwd_fb<<<dim3(B), dim3(128), 0, stream>>>(theta, A, out);
    bwd_fb<<<dim3(B), dim3(128), 0, stream>>>(theta, A, out);
  }
}

// Round 2
// 239.402 us; speedup vs baseline: 1.3967x; 1.2554x over previous
//
#include <hip/hip_runtime.h>

#define HNEG (-1000000000.0f)

constexpr int Nc = 128;
constexpr int Mc = 128;
constexpr int CELLS = Nc * Mc * 3;

__device__ __forceinline__ float lse3(float a, float b, float c) {
  float mx = fmaxf(fmaxf(a, b), c);
  return mx + __logf(__expf(a - mx) + __expf(b - mx) + __expf(c - mx));
}

// Compact diagonal-major layout: diag d (= i+j) holds cells j = lo(d)..hi(d),
// stored at (offd(d) + j - lod(d)) * 3 + s within a batch block of CELLS floats.
__device__ __forceinline__ int lod(int d) { return d > 127 ? d - 127 : 0; }
__device__ __forceinline__ int offd(int d) {
  return d <= 128 ? ((d * (d + 1)) >> 1)
                  : 8256 + (d - 128) * 127 - (((d - 128) * (d - 129)) >> 1);
}

// ---------------------------------------------------------------------------
// K1: theta row-major -> theta_diag (compact diag-major). 64x64 LDS tiles.
// float4 global loads (rows are 768B-aligned contiguous runs).
// ---------------------------------------------------------------------------
__global__ __launch_bounds__(256) void transpose_kernel(
    const float* __restrict__ theta, float* __restrict__ thd) {
  const int b = blockIdx.x;
  const int tile = blockIdx.y;  // 0..3
  const int i0 = (tile >> 1) * 64, j0 = (tile & 1) * 64;
  const int t = threadIdx.x;
  __shared__ float lds[64 * 192];
  float4* lds4 = (float4*)lds;
  const float4* src4 = (const float4*)(theta + (size_t)b * CELLS);
  float* dst = thd + (size_t)b * CELLS;
  // 64 rows x 48 float4 per tile; row stride in src is 96 float4.
  const int cbase = (j0 >> 6) * 48;
  for (int f = t; f < 64 * 48; f += 256) {
    const int r = f / 48, c4 = f - r * 48;
    lds4[f] = src4[(size_t)(i0 + r) * 96 + cbase + c4];
  }
  __syncthreads();
  const int g = t >> 6, w = t & 63;
  for (int ld = g; ld < 127; ld += 4) {
    const int d = i0 + j0 + ld;
    const int ljlo = ld > 63 ? ld - 63 : 0;
    const int ljhi = ld < 63 ? ld : 63;
    const int L = (ljhi - ljlo + 1) * 3;
    const int base = (offd(d) + (j0 + ljlo) - lod(d)) * 3;
    for (int e = w; e < L; e += 64) {
      const int lj = ljlo + e / 3, s = e - (e / 3) * 3;
      dst[base + e] = lds[(ld - lj) * 192 + lj * 3 + s];
    }
  }
}

// 6 named scalars per pipeline slot (2 cols x 3 states)
#define DECL6(p) float p##0, p##1, p##2, p##3, p##4, p##5

// ---------------------------------------------------------------------------
// K2: fused fwd || bwd wavefront, 16-deep software pipeline.
// wave 0: forward recurrence; alpha written ROW-major to aw; logZ -> ws tail.
// wave 1: backward recurrence; g (=beta) written ROW-major into out.
// Combine is then a trivial streaming pass (K3).
// ---------------------------------------------------------------------------

#define F2LOAD(P, dd) do {                                                     \
    const int dc_ = (dd) > 254 ? 254 : (dd);                                   \
    const float* p_ = thd + (size_t)(offd(dc_) + jA - lod(dc_)) * 3;           \
    P##0 = p_[0]; P##1 = p_[1]; P##2 = p_[2];                                  \
    P##3 = p_[3]; P##4 = p_[4]; P##5 = p_[5];                                  \
  } while (0)

#define F2STEP(P, dd) do {                                                     \
    const int iA_ = (dd) - jA, iB_ = (dd) - jB;                                \
    float g0 = mS2 + __logf(wS20 * E00 + wS21 * E10 + wS22 * E20);             \
    float g1 = mPA + __logf(wPA0 * E01 + wPA1 * E11 + wPA2 * E21);             \
    float g2 = mS1 + __logf(wS10 * E02 + wS11 * E12 + wS12 * E22);             \
    if ((dd) == 0 && l == 0) g0 = 0.0f; /* origin: lse_m := 0 at (0,0) */      \
    float cA0 = HNEG, cA1 = HNEG, cA2 = HNEG;                                  \
    if ((unsigned)iA_ < (unsigned)Nc) {                                        \
      cA0 = P##0 + g0; cA1 = P##1 + g1; cA2 = P##2 + g2;                       \
      float* o_ = aw + (iA_ * Mc + jA) * 3;                                    \
      o_[0] = cA0; o_[1] = cA1; o_[2] = cA2;                                   \
    }                                                                          \
    float h0 = mPP + __logf(wPP0 * E00 + wPP1 * E10 + wPP2 * E20);             \
    float h1 = mPB + __logf(wPB0 * E01 + wPB1 * E11 + wPB2 * E21);             \
    float h2 = mPA + __logf(wPA0 * E02 + wPA1 * E12 + wPA2 * E22);             \
    float cB0 = HNEG, cB1 = HNEG, cB2 = HNEG;                                  \
    if ((unsigned)iB_ < (unsigned)Nc) {                                        \
      cB0 = P##3 + h0; cB1 = P##4 + h1; cB2 = P##5 + h2;                       \
      float* o_ = aw + (iB_ * Mc + jB) * 3;                                    \
      o_[0] = cB0; o_[1] = cB1; o_[2] = cB2;                                   \
    }                                                                          \
    if ((dd) == 254) { fz0 = cB0; fz1 = cB1; fz2 = cB2; }                      \
    const float mA_ = fmaxf(fmaxf(cA0, cA1), cA2);                             \
    const float a0_ = __expf(cA0 - mA_), a1_ = __expf(cA1 - mA_),              \
                a2_ = __expf(cA2 - mA_);                                       \
    const float mB_ = fmaxf(fmaxf(cB0, cB1), cB2);                             \
    const float b0_ = __expf(cB0 - mB_), b1_ = __expf(cB1 - mB_),              \
                b2_ = __expf(cB2 - mB_);                                       \
    mPP = mPA; wPP0 = wPA0; wPP1 = wPA1; wPP2 = wPA2;                          \
    mPA = mA_; wPA0 = a0_; wPA1 = a1_; wPA2 = a2_;                             \
    mPB = mB_; wPB0 = b0_; wPB1 = b1_; wPB2 = b2_;                             \
    mS2 = mS1; wS20 = wS10; wS21 = wS11; wS22 = wS12;                          \
    mS1 = __shfl_up(mB_, 1);                                                   \
    wS10 = __shfl_up(b0_, 1); wS11 = __shfl_up(b1_, 1);                        \
    wS12 = __shfl_up(b2_, 1);                                                  \
    if (l == 0) { mS1 = HNEG; wS10 = 1.f; wS11 = 1.f; wS12 = 1.f; }            \
  } while (0)

// backward-lite: no alpha loads, no logZ; stores g (=beta) row-major into ob.
#define B2LOADL(Pt, dd) do {                                                   \
    int dor_ = 254 - (dd); if (dor_ < 0) dor_ = 0;                             \
    const int base_ = (offd(dor_) + jjB - lod(dor_)) * 3;                      \
    const float* p_ = thd + base_;                                             \
    Pt##3 = p_[0]; Pt##4 = p_[1]; Pt##5 = p_[2];                               \
    Pt##0 = p_[3]; Pt##1 = p_[4]; Pt##2 = p_[5];                               \
  } while (0)

#define B2STEPL(Pt, dd) do {                                                   \
    const int iA_ = Nc - 1 - (dd) + jA;                                        \
    const int iB_ = Nc - 1 - (dd) + jB;                                        \
    float uA0 = HNEG, uA1 = HNEG, uA2 = HNEG;                                  \
    {                                                                          \
      const float v0 = S2u0, v1 = pAu1, v2 = S1u2;                             \
      const float mv = fmaxf(fmaxf(v0, v1), v2);                               \
      const float w0 = __expf(v0 - mv), w1 = __expf(v1 - mv),                  \
                  w2 = __expf(v2 - mv);                                        \
      float g0 = mv + __logf(w0 * E00 + w1 * E01 + w2 * E02);                  \
      float g1 = mv + __logf(w0 * E10 + w1 * E11 + w2 * E12);                  \
      float g2 = mv + __logf(w0 * E20 + w1 * E21 + w2 * E22);                  \
      if ((dd) == 0 && l == 0) { g0 = 0.f; g1 = 0.f; g2 = 0.f; }               \
      if ((unsigned)iA_ < (unsigned)Nc) {                                      \
        uA0 = g0 + Pt##0; uA1 = g1 + Pt##1; uA2 = g2 + Pt##2;                  \
        float* o_ = ob + (iA_ * Mc + jjA) * 3;                                 \
        o_[0] = g0; o_[1] = g1; o_[2] = g2;                                    \
      }                                                                        \
    }                                                                          \
    float uB0 = HNEG, uB1 = HNEG, uB2 = HNEG;                                  \
    {                                                                          \
      const float v0 = ppAu0, v1 = pBu1, v2 = pAu2;                            \
      const float mv = fmaxf(fmaxf(v0, v1), v2);                               \
      const float w0 = __expf(v0 - mv), w1 = __expf(v1 - mv),                  \
                  w2 = __expf(v2 - mv);                                        \
      const float g0 = mv + __logf(w0 * E00 + w1 * E01 + w2 * E02);            \
      const float g1 = mv + __logf(w0 * E10 + w1 * E11 + w2 * E12);            \
      const float g2 = mv + __logf(w0 * E20 + w1 * E21 + w2 * E22);            \
      if ((unsigned)iB_ < (unsigned)Nc) {                                      \
        uB0 = g0 + Pt##3; uB1 = g1 + Pt##4; uB2 = g2 + Pt##5;                  \
        float* o_ = ob + (iB_ * Mc + jjB) * 3;                                 \
        o_[0] = g0; o_[1] = g1; o_[2] = g2;                                    \
      }                                                                        \
    }                                                                          \
    ppAu0 = pAu0; pAu0 = uA0; pAu1 = uA1; pAu2 = uA2; pBu1 = uB1;              \
    S2u0 = S1u0;                                                               \
    S1u0 = __shfl_up(uB0, 1);                                                  \
    S1u2 = __shfl_up(uB2, 1);                                                  \
    if (l == 0) { S1u0 = HNEG; S1u2 = HNEG; }                                  \
  } while (0)

__global__ __launch_bounds__(128, 1) void fb2_kernel(
    const float* __restrict__ thd_, const float* __restrict__ A,
    float* __restrict__ aw_, float* __restrict__ logZ_ws,
    float* __restrict__ ob_) {
  const int b = blockIdx.x;
  const int wave = threadIdx.x >> 6;
  const int l = threadIdx.x & 63;
  const float* thd = thd_ + (size_t)b * CELLS;
  const float* Ab = A + b * 9;
  const float E00 = __expf(Ab[0]), E01 = __expf(Ab[1]), E02 = __expf(Ab[2]);
  const float E10 = __expf(Ab[3]), E11 = __expf(Ab[4]), E12 = __expf(Ab[5]);
  const float E20 = __expf(Ab[6]), E21 = __expf(Ab[7]), E22 = __expf(Ab[8]);

  const int jA = 2 * l, jB = 2 * l + 1;

  if (wave == 0) {
    // ----------------- forward -----------------
    float* aw = aw_ + (size_t)b * CELLS;

    float mPA = HNEG, wPA0 = 1.f, wPA1 = 1.f, wPA2 = 1.f;
    float mPB = HNEG, wPB0 = 1.f, wPB1 = 1.f, wPB2 = 1.f;
    float mPP = HNEG, wPP0 = 1.f, wPP1 = 1.f, wPP2 = 1.f;
    float mS1 = HNEG, wS10 = 1.f, wS11 = 1.f, wS12 = 1.f;
    float mS2 = HNEG, wS20 = 1.f, wS21 = 1.f, wS22 = 1.f;
    float fz0 = HNEG, fz1 = HNEG, fz2 = HNEG;

    DECL6(s00); DECL6(s01); DECL6(s02); DECL6(s03);
    DECL6(s04); DECL6(s05); DECL6(s06); DECL6(s07);
    DECL6(s08); DECL6(s09); DECL6(s10); DECL6(s11);
    DECL6(s12); DECL6(s13); DECL6(s14); DECL6(s15);

    F2LOAD(s00, 0);  F2LOAD(s01, 1);  F2LOAD(s02, 2);  F2LOAD(s03, 3);
    F2LOAD(s04, 4);  F2LOAD(s05, 5);  F2LOAD(s06, 6);  F2LOAD(s07, 7);
    F2LOAD(s08, 8);  F2LOAD(s09, 9);  F2LOAD(s10, 10); F2LOAD(s11, 11);
    F2LOAD(s12, 12); F2LOAD(s13, 13); F2LOAD(s14, 14); F2LOAD(s15, 15);

    for (int t = 0; t < 16; ++t) {
      const int d0 = 16 * t;
      F2STEP(s00, d0 + 0);  F2STEP(s01, d0 + 1);  F2STEP(s02, d0 + 2);  F2STEP(s03, d0 + 3);
      F2LOAD(s00, d0 + 16); F2LOAD(s01, d0 + 17); F2LOAD(s02, d0 + 18); F2LOAD(s03, d0 + 19);
      F2STEP(s04, d0 + 4);  F2STEP(s05, d0 + 5);  F2STEP(s06, d0 + 6);  F2STEP(s07, d0 + 7);
      F2LOAD(s04, d0 + 20); F2LOAD(s05, d0 + 21); F2LOAD(s06, d0 + 22); F2LOAD(s07, d0 + 23);
      F2STEP(s08, d0 + 8);  F2STEP(s09, d0 + 9);  F2STEP(s10, d0 + 10); F2STEP(s11, d0 + 11);
      F2LOAD(s08, d0 + 24); F2LOAD(s09, d0 + 25); F2LOAD(s10, d0 + 26); F2LOAD(s11, d0 + 27);
      F2STEP(s12, d0 + 12); F2STEP(s13, d0 + 13); F2STEP(s14, d0 + 14); F2STEP(s15, d0 + 15);
      F2LOAD(s12, d0 + 28); F2LOAD(s13, d0 + 29); F2LOAD(s14, d0 + 30); F2LOAD(s15, d0 + 31);
    }
    if (l == 63) logZ_ws[b] = lse3(fz0, fz1, fz2);
  } else {
    // ----------------- backward (beta only) -----------------
    float* ob = ob_ + (size_t)b * CELLS;
    const int jjA = Mc - 1 - jA, jjB = Mc - 1 - jB;  // orig cols

    float pAu0 = HNEG, pAu1 = HNEG, pAu2 = HNEG;
    float ppAu0 = HNEG, pBu1 = HNEG;
    float S1u0 = HNEG, S1u2 = HNEG, S2u0 = HNEG;

    DECL6(s00); DECL6(s01); DECL6(s02); DECL6(s03);
    DECL6(s04); DECL6(s05); DECL6(s06); DECL6(s07);
    DECL6(s08); DECL6(s09); DECL6(s10); DECL6(s11);
    DECL6(s12); DECL6(s13); DECL6(s14); DECL6(s15);

    B2LOADL(s00, 0);  B2LOADL(s01, 1);  B2LOADL(s02, 2);  B2LOADL(s03, 3);
    B2LOADL(s04, 4);  B2LOADL(s05, 5);  B2LOADL(s06, 6);  B2LOADL(s07, 7);
    B2LOADL(s08, 8);  B2LOADL(s09, 9);  B2LOADL(s10, 10); B2LOADL(s11, 11);
    B2LOADL(s12, 12); B2LOADL(s13, 13); B2LOADL(s14, 14); B2LOADL(s15, 15);

    for (int t = 0; t < 16; ++t) {
      const int d0 = 16 * t;
      B2STEPL(s00, d0 + 0);  B2STEPL(s01, d0 + 1);  B2STEPL(s02, d0 + 2);  B2STEPL(s03, d0 + 3);
      B2LOADL(s00, d0 + 16); B2LOADL(s01, d0 + 17); B2LOADL(s02, d0 + 18); B2LOADL(s03, d0 + 19);
      B2STEPL(s04, d0 + 4);  B2STEPL(s05, d0 + 5);  B2STEPL(s06, d0 + 6);  B2STEPL(s07, d0 + 7);
      B2LOADL(s04, d0 + 20); B2LOADL(s05, d0 + 21); B2LOADL(s06, d0 + 22); B2LOADL(s07, d0 + 23);
      B2STEPL(s08, d0 + 8);  B2STEPL(s09, d0 + 9);  B2STEPL(s10, d0 + 10); B2STEPL(s11, d0 + 11);
      B2LOADL(s08, d0 + 24); B2LOADL(s09, d0 + 25); B2LOADL(s10, d0 + 26); B2LOADL(s11, d0 + 27);
      B2STEPL(s12, d0 + 12); B2STEPL(s13, d0 + 13); B2STEPL(s14, d0 + 14); B2STEPL(s15, d0 + 15);
      B2LOADL(s12, d0 + 28); B2LOADL(s13, d0 + 29); B2LOADL(s14, d0 + 30); B2LOADL(s15, d0 + 31);
    }
  }
}

// ---------------------------------------------------------------------------
// K3: streaming combine. out holds g (beta) row-major; aw holds alpha
// row-major. out = g + alpha - logZ, pure float4 streaming.
// grid (B, 12), 256 threads, 4 float4 per thread (12288 f4 per batch).
// ---------------------------------------------------------------------------
__global__ __launch_bounds__(256) void combine_kernel(
    const float4* __restrict__ aw4, const float* __restrict__ logZ_ws,
    float4* __restrict__ out4) {
  const int b = blockIdx.x;
  const float lz = logZ_ws[b];
  const size_t base =
      (size_t)b * 12288 + (size_t)blockIdx.y * 1024 + threadIdx.x;
#pragma unroll
  for (int k = 0; k < 4; ++k) {
    const size_t idx = base + (size_t)k * 256;
    const float4 a = aw4[idx];
    const float4 g = out4[idx];
    out4[idx] = make_float4(a.x + g.x - lz, a.y + g.y - lz, a.z + g.z - lz,
                            a.w + g.w - lz);
  }
}

// ---------------------------------------------------------------------------
// Fallback (round-2 structure, known-correct ~355 us): used only if ws small.
// ---------------------------------------------------------------------------
__global__ __launch_bounds__(128) void fwd_fb(const float* __restrict__ theta,
                                              const float* __restrict__ A,
                                              float* __restrict__ out) {
  const int b = blockIdx.x;
  const int j = threadIdx.x;
  const float* th = theta + (size_t)b * CELLS;
  float* ob = out + (size_t)b * CELLS;

  __shared__ float sA[9];
  __shared__ float ring[3][Mc + 1][3];
  if (j < 9) sA[j] = A[b * 9 + j];
  {
    float* rf = &ring[0][0][0];
    for (int t = j; t < 3 * (Mc + 1) * 3; t += Mc) rf[t] = HNEG;
  }
  __syncthreads();
  const float A00 = sA[0], A01 = sA[1], A02 = sA[2];
  const float A10 = sA[3], A11 = sA[4], A12 = sA[5];
  const float A20 = sA[6], A21 = sA[7], A22 = sA[8];

  float p0 = HNEG, p1 = HNEG, p2 = HNEG;
  float tc0 = 0.f, tc1 = 0.f, tc2 = 0.f, tn0 = 0.f, tn1 = 0.f, tn2 = 0.f;
  if (j == 0) { tc0 = th[0]; tc1 = th[1]; tc2 = th[2]; }
  if (j <= 1) {
    const int i1 = 1 - j;
    const float* p = th + (i1 * Mc + j) * 3;
    tn0 = p[0]; tn1 = p[1]; tn2 = p[2];
  }
  int s0 = 0, s1 = 2, s2 = 1;
  for (int d = 0; d < Nc + Mc - 1; ++d) {
    const int i = d - j;
    float tf0 = 0.f, tf1 = 0.f, tf2 = 0.f;
    const int ip = i + 2;
    if (ip >= 0 && ip < Nc) {
      const float* p = th + (ip * Mc + j) * 3;
      tf0 = p[0]; tf1 = p[1]; tf2 = p[2];
    }
    float c0 = HNEG, c1 = HNEG, c2 = HNEG;
    if (i >= 0 && i < Nc) {
      const float* nd1 = ring[s1][j];
      const float* nd2 = ring[s2][j];
      float lm = lse3(nd2[0] + A00, nd2[1] + A10, nd2[2] + A20);
      if (i == 0 && j == 0) lm = 0.0f;
      float lx = lse3(p0 + A01, p1 + A11, p2 + A21);
      float ly = lse3(nd1[0] + A02, nd1[1] + A12, nd1[2] + A22);
      c0 = tc0 + lm; c1 = tc1 + lx; c2 = tc2 + ly;
      float* o = ob + (i * Mc + j) * 3;
      o[0] = c0; o[1] = c1; o[2] = c2;
    }
    float* w = ring[s0][j + 1];
    w[0] = c0; w[1] = c1; w[2] = c2;
    __syncthreads();
    p0 = c0; p1 = c1; p2 = c2;
    tc0 = tn0; tc1 = tn1; tc2 = tn2;
    tn0 = tf0; tn1 = tf1; tn2 = tf2;
    const int t = s2; s2 = s1; s1 = s0; s0 = t;
  }
}

__global__ __launch_bounds__(128) void bwd_fb(const float* __restrict__ theta,
                                              const float* __restrict__ A,
                                              float* __restrict__ ob_) {
  const int b = blockIdx.x;
  const int q = threadIdx.x;
  const float* th = theta + (size_t)b * CELLS;
  float* ob = ob_ + (size_t)b * CELLS;

  __shared__ float sA[9];
  __shared__ float ring[3][Mc + 1][3];
  __shared__ float sZ;
  if (q < 9) sA[q] = A[b * 9 + q];
  {
    float* rf = &ring[0][0][0];
    for (int t = q; t < 3 * (Mc + 1) * 3; t += Mc) rf[t] = HNEG;
  }
  if (q == 0) {
    sZ = lse3(ob[(Nc * Mc - 1) * 3 + 0], ob[(Nc * Mc - 1) * 3 + 1],
              ob[(Nc * Mc - 1) * 3 + 2]);
  }
  __syncthreads();
  const float A00 = sA[0], A01 = sA[1], A02 = sA[2];
  const float A10 = sA[3], A11 = sA[4], A12 = sA[5];
  const float A20 = sA[6], A21 = sA[7], A22 = sA[8];
  const float logZ = sZ;

  const int jj = Mc - 1 - q;
  float pu1 = HNEG;
  float tc0 = 0.f, tc1 = 0.f, tc2 = 0.f, tn0 = 0.f, tn1 = 0.f, tn2 = 0.f;
  float ac0 = 0.f, ac1 = 0.f, ac2 = 0.f, an0 = 0.f, an1 = 0.f, an2 = 0.f;
  if (q == 0) {
    const float* p = th + ((Nc - 1) * Mc + jj) * 3;
    tc0 = p[0]; tc1 = p[1]; tc2 = p[2];
    const float* a = ob + ((Nc - 1) * Mc + jj) * 3;
    ac0 = a[0]; ac1 = a[1]; ac2 = a[2];
  }
  if (q <= 1) {
    const int i1 = Nc - 2 + q;
    const float* p = th + (i1 * Mc + jj) * 3;
    tn0 = p[0]; tn1 = p[1]; tn2 = p[2];
    const float* a = ob + (i1 * Mc + jj) * 3;
    an0 = a[0]; an1 = a[1]; an2 = a[2];
  }
  int s0 = 0, s1 = 2, s2 = 1;
  for (int d = 0; d < Nc + Mc - 1; ++d) {
    const int p = d - q;
    const int i = Nc - 1 - p;
    float tf0 = 0.f, tf1 = 0.f, tf2 = 0.f, af0 = 0.f, af1 = 0.f, af2 = 0.f;
    const int ipf = i - 2;
    if (ipf >= 0 && ipf < Nc) {
      const float* pp = th + (ipf * Mc + jj) * 3;
      tf0 = pp[0]; tf1 = pp[1]; tf2 = pp[2];
      const float* aa = ob + (ipf * Mc + jj) * 3;
      af0 = aa[0]; af1 = aa[1]; af2 = aa[2];
    }
    float u0 = HNEG, u1 = HNEG, u2 = HNEG;
    if (p >= 0 && p < Nc) {
      const float* nd1 = ring[s1][q];
      const float* nd2 = ring[s2][q];
      const float v0 = nd2[0];
      const float v1 = pu1;
      const float v2 = nd1[2];
      float g0 = lse3(A00 + v0, A01 + v1, A02 + v2);
      float g1 = lse3(A10 + v0, A11 + v1, A12 + v2);
      float g2 = lse3(A20 + v0, A21 + v1, A22 + v2);
      if (p == 0 && q == 0) { g0 = 0.0f; g1 = 0.0f; g2 = 0.0f; }
      u0 = g0 + tc0; u1 = g1 + tc1; u2 = g2 + tc2;
      float* o = ob + (i * Mc + jj) * 3;
      o[0] = ac0 + g0 - logZ;
      o[1] = ac1 + g1 - logZ;
      o[2] = ac2 + g2 - logZ;
    }
    float* w = ring[s0][q + 1];
    w[0] = u0; w[1] = u1; w[2] = u2;
    __syncthreads();
    pu1 = u1;
    tc0 = tn0; tc1 = tn1; tc2 = tn2;
    tn0 = tf0; tn1 = tf1; tn2 = tf2;
    ac0 = an0; ac1 = an1; ac2 = an2;
    an0 = af0; an1 = af1; an2 = af2;
    const int t = s2; s2 = s1; s1 = s0; s0 = t;
  }
}

extern "C" void kernel_launch(void* const* d_in, const int* in_sizes, int n_in,
                              void* d_out, int out_size, void* d_ws, size_t ws_size,
                              hipStream_t stream) {
  const float* theta = (const float*)d_in[0];
  const float* A = (const float*)d_in[1];
  float* out = (float*)d_out;
  const int B = in_sizes[1] / 9;  // A is (B, 3, 3)

  const size_t need = (size_t)B * CELLS * 8 + (size_t)B * 4;  // thd + aw + logZ
  if (ws_size >= need) {
    float* thd = (float*)d_ws;
    float* aw = thd + (size_t)B * CELLS;
    float* logZ_ws = aw + (size_t)B * CELLS;
    transpose_kernel<<<dim3(B, 4), dim3(256), 0, stream>>>(theta, thd);
    fb2_kernel<<<dim3(B), dim3(128), 0, stream>>>(thd, A, aw, logZ_ws, out);
    combine_kernel<<<dim3(B, 12), dim3(256), 0, stream>>>(
        (const float4*)aw, logZ_ws, (float4*)out);
  } else {
    fwd_fb<<<dim3(B), dim3(128), 0, stream>>>(theta, A, out);
    bwd_fb<<<dim3(B), dim3(128), 0, stream>>>(theta, A, out);
  }
}